// Round 9
// baseline (61.196 us; speedup 1.0000x reference)
//
#include <hip/hip_runtime.h>

// softmax(ALPHA*|x-bins|) over K=32 bins + weighted-sum code.
// Memory-bound: ~286 MB traffic. Ladder: 65.3 -> 61.1 (DPP) -> 54.0us
// (raw v_exp, UNROLL=4). UNROLL=8 regressed (57.1).
// R8: 4-lane/8-bin layout. Each lane owns 8 bins (2 f32x4), elements span
//     4 lanes -> quad_perm DPP butterflies need only 2 stages (was 3),
//     in-lane 8-wide v_min3 trees, x redundancy halved. Each lane stores
//     32B contiguous (2 dwordx4); wave covers 4KiB contiguous per iter.

#define SSQ_SCALE (-432.80854f)   // ALPHA * log2(e) = -300 * 1.4426950408889634
#define SSQ_UNROLL 2              // elements per thread

typedef float f32x4 __attribute__((ext_vector_type(4)));

template <int CTRL>
__device__ __forceinline__ float dpp_f(float v) {
    int i = __builtin_bit_cast(int, v);
    i = __builtin_amdgcn_update_dpp(i, i, CTRL, 0xf, 0xf, true);
    return __builtin_bit_cast(float, i);
}
#define DPP_XOR1  0xB1   // quad_perm [1,0,3,2]
#define DPP_XOR2  0x4E   // quad_perm [2,3,0,1]

__device__ __forceinline__ float red4_min(float v) {
    v = fminf(v, dpp_f<DPP_XOR1>(v));   // GCNDPPCombine fuses mov+min
    v = fminf(v, dpp_f<DPP_XOR2>(v));
    return v;
}
__device__ __forceinline__ float red4_sum(float v) {
    v += dpp_f<DPP_XOR1>(v);
    v += dpp_f<DPP_XOR2>(v);
    return v;
}

__global__ __launch_bounds__(256) void ssq_kernel(
    const float* __restrict__ x,      // n elements (B*L)
    const float* __restrict__ bins,   // K = 32
    float* __restrict__ soft,         // n*32 (viewed as n*8 float4s)
    float* __restrict__ code)         // n
{
    const int sub = threadIdx.x & 3;                 // which 8-bin octet
    const f32x4 bA = reinterpret_cast<const f32x4*>(bins)[sub * 2];
    const f32x4 bB = reinterpret_cast<const f32x4*>(bins)[sub * 2 + 1];
    f32x4* __restrict__ soft4 = reinterpret_cast<f32x4*>(soft);

    // block covers 64*UNROLL elements; exact cover, no bounds checks.
    const int e0 = blockIdx.x * (64 * SSQ_UNROLL) + (threadIdx.x >> 2);

    float xv[SSQ_UNROLL];
    #pragma unroll
    for (int u = 0; u < SSQ_UNROLL; ++u)
        xv[u] = x[e0 + u * 64];

    #pragma unroll
    for (int u = 0; u < SSQ_UNROLL; ++u) {
        const int e = e0 + u * 64;
        const float xu = xv[u];

        // signed diffs; abs folds into VOP3 input modifiers
        const float t0 = xu - bA.x, t1 = xu - bA.y;
        const float t2 = xu - bA.z, t3 = xu - bA.w;
        const float t4 = xu - bB.x, t5 = xu - bB.y;
        const float t6 = xu - bB.z, t7 = xu - bB.w;

        // in-lane min of 8 |t| via min3 tree, then 2-stage quad butterfly
        const float mA = __builtin_fminf(
            fminf(fminf(fabsf(t0), fabsf(t1)), fminf(fabsf(t2), fabsf(t3))),
            fminf(fminf(fabsf(t4), fabsf(t5)), fminf(fabsf(t6), fabsf(t7))));
        const float dmin = red4_min(mA);

        // e_k = 2^(SCALE*(|t_k| - dmin)); raw v_exp_f32, FTZ for far bins
        const float moff = -SSQ_SCALE * dmin;
        const float e0v = __builtin_amdgcn_exp2f(fmaf(SSQ_SCALE, fabsf(t0), moff));
        const float e1v = __builtin_amdgcn_exp2f(fmaf(SSQ_SCALE, fabsf(t1), moff));
        const float e2v = __builtin_amdgcn_exp2f(fmaf(SSQ_SCALE, fabsf(t2), moff));
        const float e3v = __builtin_amdgcn_exp2f(fmaf(SSQ_SCALE, fabsf(t3), moff));
        const float e4v = __builtin_amdgcn_exp2f(fmaf(SSQ_SCALE, fabsf(t4), moff));
        const float e5v = __builtin_amdgcn_exp2f(fmaf(SSQ_SCALE, fabsf(t5), moff));
        const float e6v = __builtin_amdgcn_exp2f(fmaf(SSQ_SCALE, fabsf(t6), moff));
        const float e7v = __builtin_amdgcn_exp2f(fmaf(SSQ_SCALE, fabsf(t7), moff));

        // joint reductions: denominator and weighted-bin numerator
        const float sum = red4_sum(((e0v + e1v) + (e2v + e3v)) +
                                   ((e4v + e5v) + (e6v + e7v)));
        const float num = red4_sum(((e0v * bA.x + e1v * bA.y) +
                                    (e2v * bA.z + e3v * bA.w)) +
                                   ((e4v * bB.x + e5v * bB.y) +
                                    (e6v * bB.z + e7v * bB.w)));

        const float inv = __builtin_amdgcn_rcpf(sum);
        f32x4 w0, w1;
        w0.x = e0v * inv; w0.y = e1v * inv; w0.z = e2v * inv; w0.w = e3v * inv;
        w1.x = e4v * inv; w1.y = e5v * inv; w1.z = e6v * inv; w1.w = e7v * inv;

        // lane writes 32B contiguous; wave covers 4KiB contiguous per iter
        const int q = e * 8 + sub * 2;
        soft4[q]     = w0;
        soft4[q + 1] = w1;

        if (sub == 0) code[e] = num * inv;
    }
}

extern "C" void kernel_launch(void* const* d_in, const int* in_sizes, int n_in,
                              void* d_out, int out_size, void* d_ws, size_t ws_size,
                              hipStream_t stream) {
    const float* x    = (const float*)d_in[0];   // (B, L, 1) f32
    const float* bins = (const float*)d_in[1];   // (K,) f32, K == 32
    const int n = in_sizes[0];                   // B*L = 2,097,152

    float* soft = (float*)d_out;                 // (B, L, 32)
    float* code = soft + (size_t)n * 32;         // (B, L, 1)

    const int grid = n / (64 * SSQ_UNROLL);      // 16384, exact cover
    ssq_kernel<<<grid, 256, 0, stream>>>(x, bins, soft, code);
}

// Round 10
// 51.514 us; speedup vs baseline: 1.1880x; 1.1880x over previous
//
#include <hip/hip_runtime.h>

// softmax(ALPHA*|x-bins|) over K=32 bins + weighted-sum code.
// Memory-bound: ~286 MB traffic. Ladder: 65.3 -> 61.1 (DPP) -> 54.0us
// (R6: raw v_exp, UNROLL=4, 8-lane/4-bin, dense 16B/lane stores).
// Failed probes: UNROLL=8 (57.1, VGPR-confounded), 4-lane/8-bin (61.2,
// store shape), LDS transpose (80.5), persistent chunks (83.5).
// R9: R6 compute EXACTLY, but 512-thread blocks -> 8192 blocks (half the
//     cold prologues, 32KiB contiguous/block), per-thread state unchanged.
//     Clean deconfound of the block-lifecycle-overhead theory.

#define SSQ_SCALE (-432.80854f)   // ALPHA * log2(e) = -300 * 1.4426950408889634
#define SSQ_UNROLL 4
#define SSQ_BLK 512

typedef float f32x4 __attribute__((ext_vector_type(4)));

template <int CTRL>
__device__ __forceinline__ float dpp_f(float v) {
    int i = __builtin_bit_cast(int, v);
    i = __builtin_amdgcn_update_dpp(i, i, CTRL, 0xf, 0xf, true);
    return __builtin_bit_cast(float, i);
}
#define DPP_XOR1  0xB1   // quad_perm [1,0,3,2]
#define DPP_XOR2  0x4E   // quad_perm [2,3,0,1]
#define DPP_HMIRR 0x141  // row_half_mirror: lane i <-> 7-i within each 8

__device__ __forceinline__ float red8_min(float v) {
    v = fminf(v, dpp_f<DPP_XOR1>(v));   // GCNDPPCombine fuses mov+min
    v = fminf(v, dpp_f<DPP_XOR2>(v));
    v = fminf(v, dpp_f<DPP_HMIRR>(v));
    return v;
}
__device__ __forceinline__ float red8_sum(float v) {
    v += dpp_f<DPP_XOR1>(v);
    v += dpp_f<DPP_XOR2>(v);
    v += dpp_f<DPP_HMIRR>(v);
    return v;
}

__global__ __launch_bounds__(SSQ_BLK) void ssq_kernel(
    const float* __restrict__ x,      // n elements (B*L)
    const float* __restrict__ bins,   // K = 32
    float* __restrict__ soft,         // n*32 (viewed as n*8 float4s)
    float* __restrict__ code)         // n
{
    const int sub = threadIdx.x & 7;                 // which float4 of the 32 k's
    const f32x4 b4 = reinterpret_cast<const f32x4*>(bins)[sub];
    f32x4* __restrict__ soft4 = reinterpret_cast<f32x4*>(soft);

    const int base = blockIdx.x * (SSQ_BLK * SSQ_UNROLL) + threadIdx.x;

    // exact cover: grid*SSQ_BLK*UNROLL == n*8, no bounds checks anywhere.
    // all x loads issued before any compute (MLP; 8 lanes share each value)
    float xv[SSQ_UNROLL];
    #pragma unroll
    for (int u = 0; u < SSQ_UNROLL; ++u)
        xv[u] = x[(base + u * SSQ_BLK) >> 3];

    #pragma unroll
    for (int u = 0; u < SSQ_UNROLL; ++u) {
        const int f = base + u * SSQ_BLK;
        const float xu = xv[u];

        // signed diffs; abs folds into VOP3 input modifiers of min/fma
        const float t0 = xu - b4.x;
        const float t1 = xu - b4.y;
        const float t2 = xu - b4.z;
        const float t3 = xu - b4.w;

        // local min of |t| (v_min3 + abs mods), then 8-lane DPP butterfly
        const float dmin = red8_min(
            fminf(fminf(fabsf(t0), fabsf(t1)), fminf(fabsf(t2), fabsf(t3))));

        // e_k = 2^(SCALE*(|t_k| - dmin)); raw v_exp_f32, FTZ for far bins
        const float moff = -SSQ_SCALE * dmin;
        const float e0 = __builtin_amdgcn_exp2f(fmaf(SSQ_SCALE, fabsf(t0), moff));
        const float e1 = __builtin_amdgcn_exp2f(fmaf(SSQ_SCALE, fabsf(t1), moff));
        const float e2 = __builtin_amdgcn_exp2f(fmaf(SSQ_SCALE, fabsf(t2), moff));
        const float e3 = __builtin_amdgcn_exp2f(fmaf(SSQ_SCALE, fabsf(t3), moff));

        // joint reductions: denominator and weighted-bin numerator
        const float sum = red8_sum((e0 + e1) + (e2 + e3));
        const float num = red8_sum((e0 * b4.x + e1 * b4.y) +
                                   (e2 * b4.z + e3 * b4.w));

        const float inv = __builtin_amdgcn_rcpf(sum);
        f32x4 w;
        w.x = e0 * inv; w.y = e1 * inv; w.z = e2 * inv; w.w = e3 * inv;
        soft4[f] = w;                                // contiguous 1KiB/wave

        if (sub == 0) code[f >> 3] = num * inv;
    }
}

extern "C" void kernel_launch(void* const* d_in, const int* in_sizes, int n_in,
                              void* d_out, int out_size, void* d_ws, size_t ws_size,
                              hipStream_t stream) {
    const float* x    = (const float*)d_in[0];   // (B, L, 1) f32
    const float* bins = (const float*)d_in[1];   // (K,) f32, K == 32
    const int n = in_sizes[0];                   // B*L = 2,097,152

    float* soft = (float*)d_out;                 // (B, L, 32)
    float* code = soft + (size_t)n * 32;         // (B, L, 1)

    const int total_vec = n * 8;                 // 16,777,216 float4s
    const int grid = total_vec / (SSQ_BLK * SSQ_UNROLL);   // 8192, exact
    ssq_kernel<<<grid, SSQ_BLK, 0, stream>>>(x, bins, soft, code);
}